// Round 8
// baseline (74.826 us; speedup 1.0000x reference)
//
#include <hip/hip_runtime.h>

// B=8, H=W=256, single channel. Output: one fp32 scalar (composite loss).
#define HW_ELEMS 65536
#define BIGD 1e4f
#define EPSL 1e-8f
#define NBLK 1024   // one block per (b, y-pair): b = blk>>7, y0 = (blk&127)*2

__device__ __forceinline__ float waveSum(float v) {
  #pragma unroll
  for (int off = 32; off > 0; off >>= 1) v += __shfl_down(v, off);
  return v;
}

// partial layout (SoA): partial[q*NBLK + blk], q:
//   0 = inter (sum p*t), 1 = sum_p, 2 = sum_t, 3 = attn sse, 4 = boundary (ungated)
// No atomics: each block writes its own 5 slots; 1-block finalize reduces.
//
// 2 rows per block: one 18-tall column window [y0-8, y0+9] per thread contains
// the full symmetric radius-8 ball for BOTH rows -> per-pixel load count
// halves and all per-block fixed costs (barriers, reduction chains, partial
// stores) amortize over 2 rows. Exact EDT:
//  - window scan gives min distance over all probed pixels; a found value
//    v <= 8 is the true column min (all unprobed pixels are at radius > 8).
//  - tail loop (r=9..) uses the STRICT dominance break (dpos<r && dneg<r),
//    so asymmetric window probes (radius-9 upper bounds) never cause a
//    premature break. Same for the row envelope (break when r^2 dominates).
__global__ __launch_bounds__(256) void fused_kernel(
    const float* __restrict__ probs, const int* __restrict__ targets,
    const float* __restrict__ attn, float* __restrict__ partial) {
  const int blk = blockIdx.x;
  const int b = blk >> 7;
  const int y0 = (blk & 127) * 2;
  const int x = threadIdx.x;
  const int* __restrict__ timg = targets + b * HW_ELEMS;

  const int base = b * HW_ELEMS + y0 * 256 + x;
  const float p0 = probs[base], p1 = probs[base + 256];
  const float a0 = attn[base],  a1 = attn[base + 256];

  // ---- column window [y0-8, y0+9], 18 unconditional probes ----
  int w[18];
  #pragma unroll
  for (int j = 0; j < 18; ++j) {
    const int yy = y0 - 8 + j;
    w[j] = (yy >= 0 && yy < 256) ? timg[yy * 256 + x] : -1;  // -1 = OOB
  }
  const float tf0 = (w[8] == 1) ? 1.f : 0.f;
  const float tf1 = (w[9] == 1) ? 1.f : 0.f;

  // ---- phase 1: column distances for both rows from the window ----
  float dpos[2] = {BIGD, BIGD}, dneg[2] = {BIGD, BIGD};
  #pragma unroll
  for (int k = 0; k < 2; ++k) {
    const int c = 8 + k;
    #pragma unroll
    for (int j = 0; j < 18; ++j) {
      const float dy = fabsf((float)(j - c));
      if (w[j] == 1) dpos[k] = fminf(dpos[k], dy);
      else if (w[j] == 0) dneg[k] = fminf(dneg[k], dy);
    }
  }
  // rare tails (unresolved within radius 8): strict dominance break
  #pragma unroll
  for (int k = 0; k < 2; ++k) {
    const int yk = y0 + k;
    for (int r = 9; r < 256; ++r) {
      const float fr = (float)r;
      if (dpos[k] < fr && dneg[k] < fr) break;
      const int yu = yk - r, yd = yk + r;
      if (yu >= 0) {
        if (timg[yu * 256 + x]) dpos[k] = fminf(dpos[k], fr);
        else                    dneg[k] = fminf(dneg[k], fr);
      }
      if (yd < 256) {
        if (timg[yd * 256 + x]) dpos[k] = fminf(dpos[k], fr);
        else                    dneg[k] = fminf(dneg[k], fr);
      }
    }
  }

  __shared__ float g2p[2][256], g2n[2][256];
  g2p[0][x] = dpos[0] * dpos[0];
  g2n[0][x] = dneg[0] * dneg[0];
  g2p[1][x] = dpos[1] * dpos[1];
  g2n[1][x] = dneg[1] * dneg[1];
  __syncthreads();

  // ---- phase 2: row lower envelope, r=1..8 unconditional + rare tail ----
  float m2p[2], m2n[2];
  #pragma unroll
  for (int k = 0; k < 2; ++k) {
    m2p[k] = g2p[k][x];
    m2n[k] = g2n[k][x];
    #pragma unroll
    for (int j = 1; j <= 8; ++j) {
      const float rr = (float)(j * j);
      const int xl = x - j, xr = x + j;
      if (xl >= 0)  { m2p[k] = fminf(m2p[k], rr + g2p[k][xl]); m2n[k] = fminf(m2n[k], rr + g2n[k][xl]); }
      if (xr < 256) { m2p[k] = fminf(m2p[k], rr + g2p[k][xr]); m2n[k] = fminf(m2n[k], rr + g2n[k][xr]); }
    }
    for (int r = 9; r < 256; ++r) {
      const float rr0 = (float)(r * r);
      if (rr0 >= m2p[k] && rr0 >= m2n[k]) break;
      const int xl = x - r, xr = x + r;
      if (xl >= 0)  { m2p[k] = fminf(m2p[k], rr0 + g2p[k][xl]); m2n[k] = fminf(m2n[k], rr0 + g2n[k][xl]); }
      if (xr < 256) { m2p[k] = fminf(m2p[k], rr0 + g2p[k][xr]); m2n[k] = fminf(m2n[k], rr0 + g2n[k][xr]); }
    }
  }

  const float sdt0 = sqrtf(m2p[0]) + sqrtf(m2n[0]);
  const float sdt1 = sqrtf(m2p[1]) + sqrtf(m2n[1]);
  const float d0 = a0 - tf0, d1 = a1 - tf1;

  // ---- fused reductions over both rows ----
  const float v0 = waveSum(p0 * tf0 + p1 * tf1);       // inter
  const float v1 = waveSum(p0 + p1);                    // sum_p
  const float v2 = waveSum(tf0 + tf1);                  // sum_t
  const float v3 = waveSum(d0 * d0 + d1 * d1);          // sse
  const float v4 = waveSum(p0 * sdt0 + p1 * sdt1);      // boundary (ungated)

  __shared__ float lds[4][5];
  const int wid = threadIdx.x >> 6, lane = threadIdx.x & 63;
  if (lane == 0) {
    lds[wid][0] = v0; lds[wid][1] = v1; lds[wid][2] = v2;
    lds[wid][3] = v3; lds[wid][4] = v4;
  }
  __syncthreads();
  if (threadIdx.x == 0) {
    float s[5] = {0.f, 0.f, 0.f, 0.f, 0.f};
    #pragma unroll
    for (int w2 = 0; w2 < 4; ++w2)
      #pragma unroll
      for (int q = 0; q < 5; ++q) s[q] += lds[w2][q];
    #pragma unroll
    for (int q = 0; q < 5; ++q) partial[q * NBLK + blk] = s[q];  // plain stores
  }
}

// Single block, 256 threads: reduce 5*1024 partials, apply loss formula.
__global__ __launch_bounds__(256) void finalize_kernel(
    const float* __restrict__ partial, float* __restrict__ out) {
  const int tid = threadIdx.x;
  __shared__ float red[32][8];   // [qsel*8 + b][sub]
  __shared__ float sred[4];

  // per-(b,q) sums for q in {inter, sum_p, sum_t, boundary}; 128 blocks per b
  const int pair = tid >> 3, sub = tid & 7;     // 32 pairs x 8 subs
  const int qsel = pair >> 3;                    // 0..3
  const int bb = pair & 7;
  const int qoff[4] = {0, 1, 2, 4};
  const int base = qoff[qsel] * NBLK + bb * 128 + sub * 16;
  float s = 0.f;
  #pragma unroll
  for (int j = 0; j < 16; ++j) s += partial[base + j];
  red[pair][sub] = s;

  // global sse (q=3): 256 threads x 4 entries
  float e = 0.f;
  #pragma unroll
  for (int j = 0; j < 4; ++j) e += partial[3 * NBLK + tid * 4 + j];
  e = waveSum(e);
  if ((tid & 63) == 0) sred[tid >> 6] = e;
  __syncthreads();

  if (tid == 0) {
    float dsum = 0.f, tsum = 0.f, bsum = 0.f;
    for (int b2 = 0; b2 < 8; ++b2) {
      float inter = 0.f, sp = 0.f, st = 0.f, bd = 0.f;
      #pragma unroll
      for (int k = 0; k < 8; ++k) {
        inter += red[0 * 8 + b2][k];
        sp    += red[1 * 8 + b2][k];
        st    += red[2 * 8 + b2][k];
        bd    += red[3 * 8 + b2][k];
      }
      dsum += (2.f * inter + EPSL) / (sp + st + EPSL);
      const float fn = st - inter;
      const float fp = sp - inter;
      tsum += (inter + EPSL) / (inter + 0.3f * fn + 0.7f * fp + EPSL);
      bsum += (st > 0.5f) ? bd : 0.f;   // any_fg gate
    }
    const float sse = sred[0] + sred[1] + sred[2] + sred[3];
    const float dl = 1.f - dsum * 0.125f;
    const float tl = 1.f - tsum * 0.125f;
    const float bl = bsum * (1.f / 524288.f);
    const float al = sse * (1.f / 524288.f);
    out[0] = 1.0f * dl + 0.7f * tl + 0.5f * bl + 0.3f * al;
  }
}

extern "C" void kernel_launch(void* const* d_in, const int* in_sizes, int n_in,
                              void* d_out, int out_size, void* d_ws, size_t ws_size,
                              hipStream_t stream) {
  const float* probs   = (const float*)d_in[0];
  const int*   targets = (const int*)d_in[1];
  const float* attn    = (const float*)d_in[2];
  float* out = (float*)d_out;
  float* partial = (float*)d_ws;  // 5 * 1024 floats = 20 KB; fully written each call
  fused_kernel<<<NBLK, 256, 0, stream>>>(probs, targets, attn, partial);
  finalize_kernel<<<1, 256, 0, stream>>>(partial, out);
}